// Round 5
// baseline (1198.421 us; speedup 1.0000x reference)
//
#include <hip/hip_runtime.h>
#include <hip/hip_bf16.h>
#include <stdint.h>

#define M_TOTAL 8192
#define K_TOTAL 4096
#define N_TOTAL 16384
#define KB_ROW  (K_TOTAL * 2)          // bytes per row of A/B (bf16)
#define BM 256
#define BN 256
#define BK 64
#define KTILES (K_TOTAL / BK)          // 64
#define LDS_BUF 65536                  // one K-tile buffer: A 32KB + B 32KB
#define B_OFF   32768

typedef __bf16 bf16x8 __attribute__((ext_vector_type(8)));
typedef float f32x4 __attribute__((ext_vector_type(4)));
typedef unsigned short u16;
typedef u16 u16x8 __attribute__((ext_vector_type(8)));

static __device__ __forceinline__ u16 f2bf(float f) {
    unsigned int u = __builtin_bit_cast(unsigned int, f);
    u = (u + 0x7fffu + ((u >> 16) & 1u)) >> 16;   // RNE
    return (u16)u;
}

static __device__ __forceinline__ void async16(const void* g, void* l) {
    __builtin_amdgcn_global_load_lds((const __attribute__((address_space(1))) unsigned int*)g,
                                     (__attribute__((address_space(3))) unsigned int*)l,
                                     16, 0, 0);
}

// ---------------- conversion kernels ----------------

__global__ __launch_bounds__(256) void cvt_x_kernel(const float* __restrict__ x, u16* __restrict__ xb) {
    size_t i = ((size_t)blockIdx.x * 256 + threadIdx.x) * 8;
    const float4* s = reinterpret_cast<const float4*>(x + i);
    float4 a = s[0], b = s[1];
    u16x8 v;
    v[0] = f2bf(a.x); v[1] = f2bf(a.y); v[2] = f2bf(a.z); v[3] = f2bf(a.w);
    v[4] = f2bf(b.x); v[5] = f2bf(b.y); v[6] = f2bf(b.z); v[7] = f2bf(b.w);
    *reinterpret_cast<u16x8*>(xb + i) = v;
}

__global__ __launch_bounds__(256) void cvt_w_kernel(const int* __restrict__ w, u16* __restrict__ wb) {
    size_t i = ((size_t)blockIdx.x * 256 + threadIdx.x) * 8;
    const int4* s = reinterpret_cast<const int4*>(w + i);
    int4 a = s[0], b = s[1];
    u16x8 v;
    v[0] = f2bf((float)a.x); v[1] = f2bf((float)a.y); v[2] = f2bf((float)a.z); v[3] = f2bf((float)a.w);
    v[4] = f2bf((float)b.x); v[5] = f2bf((float)b.y); v[6] = f2bf((float)b.z); v[7] = f2bf((float)b.w);
    *reinterpret_cast<u16x8*>(wb + i) = v;
}

// ---------------- 256x256 GEMM, pipelined-tail overlap schedule ----------------
// Per K-tile t (buf c = t&1), Q11 of tile t-1 deferred into tile t's shadow:
//   issue rd a0,b0(t)          // 12 ds_reads in flight
//   Q11(t-1) [reg-only MFMA]   // overlaps the reads on the LDS pipe
//   issue rd a1,b1(t)          // 12 more (recycle t-1's a1/b1 regs)
//   Q00(t)  [lgkm counted by compiler]
//   Q10(t), Q01(t)
//   LGKM0; BAR#1               // all reads of buf c retired in regs
//   stage A,B(t+2)->buf c ; vmcnt ; BAR#2   // buf ~c published
// First iteration's phantom Q11 uses zeroed a1/b1 (adds 0); real last Q11
// runs after the loop. Registers: acc 128 + operands 96 -> ~240, no dbuf.

#define BAR()    { asm volatile("" ::: "memory"); __builtin_amdgcn_s_barrier(); asm volatile("" ::: "memory"); }
#define LGKM0()  asm volatile("s_waitcnt lgkmcnt(0)" ::: "memory")
#define VMC8()   asm volatile("s_waitcnt vmcnt(8)" ::: "memory")
#define VMC0()   asm volatile("s_waitcnt vmcnt(0)" ::: "memory")
#define PRIO1()  __builtin_amdgcn_s_setprio(1)
#define PRIO0()  __builtin_amdgcn_s_setprio(0)
#define SCHEDB() __builtin_amdgcn_sched_barrier(0)

#define DS_A(dst, dOff, g) { _Pragma("unroll") \
  for (int mi = 0; mi < 4; ++mi) { \
    dst[mi][0] = *(const bf16x8*)(aR + (dOff) + (g)*8192 + mi*2048 + c0); \
    dst[mi][1] = *(const bf16x8*)(aR + (dOff) + (g)*8192 + mi*2048 + c1); } }

#define DS_B(dst, dOff, g) { _Pragma("unroll") \
  for (int ni = 0; ni < 2; ++ni) { \
    dst[ni][0] = *(const bf16x8*)(bR + (dOff) + (g)*4096 + ni*2048 + c0); \
    dst[ni][1] = *(const bf16x8*)(bR + (dOff) + (g)*4096 + ni*2048 + c1); } }

// one C-quadrant (4m x 2n) over K=64: two k-slice passes of 8 indep MFMAs
#define MMA_Q(ga, gb, Aa, Bb) { \
  _Pragma("unroll") \
  for (int mi = 0; mi < 4; ++mi) { _Pragma("unroll") \
    for (int ni = 0; ni < 2; ++ni) \
      acc[(ga)*4+mi][(gb)*2+ni] = __builtin_amdgcn_mfma_f32_16x16x32_bf16(Aa[mi][0], Bb[ni][0], acc[(ga)*4+mi][(gb)*2+ni], 0, 0, 0); } \
  _Pragma("unroll") \
  for (int mi = 0; mi < 4; ++mi) { _Pragma("unroll") \
    for (int ni = 0; ni < 2; ++ni) \
      acc[(ga)*4+mi][(gb)*2+ni] = __builtin_amdgcn_mfma_f32_16x16x32_bf16(Aa[mi][1], Bb[ni][1], acc[(ga)*4+mi][(gb)*2+ni], 0, 0, 0); } }

#define STG_FULL_A(t, dOff) { _Pragma("unroll") \
  for (int c = 0; c < 4; ++c) \
    async16(aG + (size_t)(64*c)*KB_ROW + (t)*128, ldsc + (dOff) + c*8192 + tid*16); }

#define STG_FULL_B(t, dOff) { _Pragma("unroll") \
  for (int c = 0; c < 4; ++c) \
    async16(bG + (size_t)(64*c)*KB_ROW + (t)*128, ldsc + (dOff) + B_OFF + c*8192 + tid*16); }

__global__ __launch_bounds__(512, 2) void gemm256_kernel(const u16* __restrict__ A,
                                                         const u16* __restrict__ B,
                                                         const float* __restrict__ scale,
                                                         float* __restrict__ out) {
    extern __shared__ char ldsc[];
    const int tid  = threadIdx.x;
    const int lane = tid & 63;
    const int wave = tid >> 6;
    const int wm = wave >> 2;          // 0..1
    const int wn = wave & 3;           // 0..3

    // XCD-aware bijective swizzle (2048 blocks, 8 XCDs, 256-block chunks);
    // mt fastest within chunk -> 32 co-resident blocks/XCD share one B-panel.
    int orig = blockIdx.x;
    int swzid = (orig & 7) * 256 + (orig >> 3);
    int mt = swzid & 31;
    int nt = swzid >> 5;
    int m0 = mt * BM, n0 = nt * BN;

    // staging addresses (pre-swizzled global source, linear LDS dest)
    int srow = tid >> 3;                                   // 0..63
    int scol = ((tid & 7) << 4) ^ ((srow & 7) << 4);
    const char* aG = (const char*)A + (size_t)(m0 + srow) * KB_ROW + scol;
    const char* bG = (const char*)B + (size_t)(n0 + srow) * KB_ROW + scol;

    // fragment read addressing (swizzled)
    int klane = (lane >> 4) << 4;                          // 0,16,32,48
    int swz   = (lane & 7) << 4;
    int c0 = klane ^ swz;
    int c1 = (64 + klane) ^ swz;
    const char* aR = ldsc + (wm * 128 + (lane & 15)) * 128;
    const char* bR = ldsc + B_OFF + (wn * 64 + (lane & 15)) * 128;

    f32x4 acc[8][4];
    #pragma unroll
    for (int mi = 0; mi < 8; ++mi)
        #pragma unroll
        for (int ni = 0; ni < 4; ++ni)
            acc[mi][ni] = (f32x4){0.f, 0.f, 0.f, 0.f};

    bf16x8 a0[4][2], a1[4][2], b0[2][2], b1[2][2];
    // zero a1/b1 so iteration 0's phantom deferred-Q11 adds 0 to acc
    #pragma unroll
    for (int mi = 0; mi < 4; ++mi) { a1[mi][0] = (bf16x8)(__bf16)0.0f; a1[mi][1] = (bf16x8)(__bf16)0.0f; }
    #pragma unroll
    for (int ni = 0; ni < 2; ++ni) { b1[ni][0] = (bf16x8)(__bf16)0.0f; b1[ni][1] = (bf16x8)(__bf16)0.0f; }

    // prologue: tile0 -> buf0, tile1 -> buf1; drain tile0, publish buf0
    STG_FULL_A(0, 0); STG_FULL_B(0, 0);
    STG_FULL_A(1, LDS_BUF); STG_FULL_B(1, LDS_BUF);
    VMC8();
    BAR();

    for (int t = 0; t < KTILES; ++t) {
        const int dOff = (t & 1) ? LDS_BUF : 0;
        // issue first read batch (a0,b0 of tile t): 12 ds_reads in flight
        DS_A(a0, dOff, 0);
        DS_B(b0, dOff, 0);
        SCHEDB();
        // deferred tail of tile t-1 (reg-only) runs under those reads
        PRIO1(); MMA_Q(1, 1, a1, b1); PRIO0();
        SCHEDB();
        // second read batch (a1,b1 of tile t) recycles t-1's registers
        DS_A(a1, dOff, 1);
        DS_B(b1, dOff, 1);
        // quadrants of tile t (compiler inserts counted lgkm waits per use)
        PRIO1(); MMA_Q(0, 0, a0, b0); PRIO0();
        PRIO1(); MMA_Q(1, 0, a1, b0); PRIO0();
        PRIO1(); MMA_Q(0, 1, a0, b1); PRIO0();
        SCHEDB();
        LGKM0();                 // all tile-t reads retired into regs
        BAR();                   // bar#1: buf c free for overwrite
        const bool s2 = (t + 2 < KTILES);
        if (s2) { STG_FULL_A(t + 2, dOff); STG_FULL_B(t + 2, dOff); }
        if (t + 1 < KTILES) {
            if (s2) { VMC8(); } else { VMC0(); }
            BAR();               // bar#2: buf ~c published for tile t+1
        }
    }
    // final deferred tail (tile KTILES-1)
    PRIO1(); MMA_Q(1, 1, a1, b1); PRIO0();

    // epilogue: D row=(lane>>4)*4+j, col=lane&15; scale per output col
    int col0 = n0 + wn * 64 + (lane & 15);
    int row0 = m0 + wm * 128 + ((lane >> 4) << 2);
    #pragma unroll
    for (int ni = 0; ni < 4; ++ni) {
        float sc = scale[col0 + ni * 16];
        #pragma unroll
        for (int mi = 0; mi < 8; ++mi) {
            #pragma unroll
            for (int j = 0; j < 4; ++j) {
                out[(size_t)(row0 + mi * 16 + j) * N_TOTAL + (col0 + ni * 16)] = acc[mi][ni][j] * sc;
            }
        }
    }
}

// ---------------- fallback ----------------

__global__ __launch_bounds__(256) void naive_kernel(const float* __restrict__ x, const int* __restrict__ w,
                                                    const float* __restrict__ scale, float* __restrict__ out) {
    int n = blockIdx.x * 256 + threadIdx.x;
    int m = blockIdx.y;
    const float* xr = x + (size_t)m * K_TOTAL;
    const int*   wr = w + (size_t)n * K_TOTAL;
    float acc = 0.f;
    for (int k = 0; k < K_TOTAL; k += 4) {
        float4 xv = *(const float4*)(xr + k);
        int4   wv = *(const int4*)(wr + k);
        acc += xv.x * (float)wv.x + xv.y * (float)wv.y + xv.z * (float)wv.z + xv.w * (float)wv.w;
    }
    out[(size_t)m * N_TOTAL + n] = acc * scale[n];
}

extern "C" void kernel_launch(void* const* d_in, const int* in_sizes, int n_in,
                              void* d_out, int out_size, void* d_ws, size_t ws_size,
                              hipStream_t stream) {
    const float* x     = (const float*)d_in[0];
    const int*   w     = (const int*)d_in[1];
    const float* scale = (const float*)d_in[2];
    float* out = (float*)d_out;

    const size_t xb_bytes = (size_t)M_TOTAL * K_TOTAL * 2;
    const size_t wb_bytes = (size_t)N_TOTAL * K_TOTAL * 2;

    if (ws_size >= xb_bytes + wb_bytes) {
        u16* xb = (u16*)d_ws;
        u16* wb = (u16*)((char*)d_ws + xb_bytes);
        (void)hipFuncSetAttribute((const void*)gemm256_kernel,
                                  hipFuncAttributeMaxDynamicSharedMemorySize, 131072);
        cvt_x_kernel<<<(M_TOTAL * K_TOTAL) / (256 * 8), 256, 0, stream>>>(x, xb);
        cvt_w_kernel<<<(N_TOTAL * K_TOTAL) / (256 * 8), 256, 0, stream>>>(w, wb);
        gemm256_kernel<<<(M_TOTAL / BM) * (N_TOTAL / BN), 512, 131072, stream>>>(xb, wb, scale, out);
    } else {
        dim3 g(N_TOTAL / 256, M_TOTAL);
        naive_kernel<<<g, 256, 0, stream>>>(x, w, scale, out);
    }
}